// Round 5
// baseline (181.084 us; speedup 1.0000x reference)
//
#include <hip/hip_runtime.h>
#include <stdint.h>

using short8 = __attribute__((ext_vector_type(8))) short;
using f32x4  = __attribute__((ext_vector_type(4))) float;

__device__ __forceinline__ unsigned short f2bf(float f) {
    unsigned int u = __float_as_uint(f);
    unsigned int r = (u + 0x7fffu + ((u >> 16) & 1u)) >> 16;
    return (unsigned short)r;
}

// x_t layout: [n][h' 0..65][w' 0..65][k 0..255] bf16, linear (no swizzle).
// h'=h+1, w'=w+1; h'=0,65 rows and w'=0,65 cols are zero halo.
// prep blocks: [0,512) transpose ; [512,644) zero pad rows ; [644,772) zero w-halo cols ; [772,3076) build B
__global__ __launch_bounds__(256) void k_prep(const float* __restrict__ x,
                                              const float* __restrict__ wgt,
                                              unsigned short* __restrict__ xt,
                                              unsigned short* __restrict__ ball) {
    __shared__ unsigned short sm[256][72];
    int b = blockIdx.x;
    int tid = threadIdx.x;
    if (b < 512) {
        // transpose x[n][c][r][h][w] -> x_t[n][h+1][w+1][k=r*64+c]
        int n = b >> 6; int h = b & 63;
        int c = tid >> 2, r = tid & 3; int k = r * 64 + c;
        const float* src = x + ((((size_t)n * 64 + c) * 4 + r) * 64 + h) * 64;
#pragma unroll
        for (int i = 0; i < 64; i += 4) {
            float4 v = *(const float4*)(src + i);
            sm[k][i + 0] = f2bf(v.x); sm[k][i + 1] = f2bf(v.y);
            sm[k][i + 2] = f2bf(v.z); sm[k][i + 3] = f2bf(v.w);
        }
        __syncthreads();
        int w = tid & 63, kg = tid >> 6;
        unsigned short* dst = xt + ((size_t)(n * 66 + (h + 1)) * 66 + (w + 1)) * 256;
#pragma unroll
        for (int cc = 0; cc < 8; cc++) {
            int s = kg * 8 + cc;
            short8 v;
#pragma unroll
            for (int e = 0; e < 8; e++) v[e] = (short)sm[s * 8 + e][w];
            *(short8*)(dst + s * 8) = v;
        }
    } else if (b < 644) {
        // zero rows h'=0 and h'=65: 8n x 2rows x 2112 chunks(16B) = 33792 chunks
        int idx = (b - 512) * 256 + tid;
        int n = idx / 4224; int rem = idx % 4224;
        int row = rem / 2112; int c = rem % 2112;
        f32x4 z = {0.f, 0.f, 0.f, 0.f};
        *(f32x4*)((char*)xt + ((size_t)(n * 66 + (row ? 65 : 0))) * 33792 + (size_t)c * 16) = z;
    } else if (b < 772) {
        // zero cols w'=0,65 for h'=1..64: 8n x 64h x 2cols x 32 chunks = 32768
        int idx = (b - 644) * 256 + tid;
        int n = idx >> 12; int rem = idx & 4095;
        int h1 = (rem >> 6) + 1; int colsel = (rem >> 5) & 1; int c = rem & 31;
        f32x4 z = {0.f, 0.f, 0.f, 0.f};
        *(f32x4*)((char*)xt + ((size_t)(n * 66 + h1) * 66 + (colsel ? 65 : 0)) * 512 + c * 16) = z;
    } else {
        // B_all[off][col=rot*64+o][k=r*64+c] = wgt[o][c][(r-rot)&3][t(off,rot)]
        int idx = (b - 772) * 256 + tid;
        int k = idx & 255; int col = (idx >> 8) & 255; int j = idx >> 16;
        int rot = col >> 6, o = col & 63;
        int r = k >> 6, c = k & 63;
        int t = (j == 0) ? 0 : (1 + ((j - 1 - 2 * rot) & 7));
        float v = wgt[((o * 64 + c) * 4 + ((r - rot) & 3)) * 9 + t];
        ball[idx] = f2bf(v);
    }
}

// main: block d -> g=d&63 (n=g>>3, ht=g&7), rot=d>>6 (same-XCD grouping for x_t L2 reuse).
// 8 waves; wave wv owns h-row h0+wv, all 64 o, k=256. A direct from global x_t.
// LDS = 128 KB write-combine buffer [o][2KB run], XOR-swizzled 16B chunks.
__global__ __launch_bounds__(512) void k_main(const unsigned short* __restrict__ xt,
                                              const unsigned short* __restrict__ ball,
                                              float* __restrict__ out) {
    __shared__ char wb[131072];
    int d = blockIdx.x; int g = d & 63; int rot = d >> 6;
    int n = g >> 3; int ht = g & 7; int h0 = ht * 8;
    int tid = threadIdx.x; int wv = tid >> 6; int l = tid & 63;
    int l15 = l & 15; int l4 = l >> 4;
    int h = h0 + wv;
    const char* xb = (const char*)xt;
    const char* bb = (const char*)ball;

#pragma unroll 1
    for (int j = 0; j < 9; j++) {
        int dy = ((0x1A901 >> (2 * j)) & 3) - 1;
        int dx = ((0x01A91 >> (2 * j)) & 3) - 1;
        int t = (j == 0) ? 0 : (1 + ((j - 1 - 2 * rot) & 7));
        const char* arow = xb + ((size_t)(n * 66 + (h + 1 + dy)) * 66 + (dx + 1)) * 512;
        const char* brow = bb + j * 131072 + (rot * 64 + l15) * 512 + l4 * 16;

        f32x4 acc[4][4];
#pragma unroll
        for (int a = 0; a < 4; a++)
#pragma unroll
            for (int b2 = 0; b2 < 4; b2++) acc[a][b2] = (f32x4){0.f, 0.f, 0.f, 0.f};

#pragma unroll
        for (int ks = 0; ks < 8; ks++) {
            short8 Af[4], Bf[4];
#pragma unroll
            for (int mt = 0; mt < 4; mt++)
                Af[mt] = *(const short8*)(arow + (mt * 16 + l15) * 512 + (ks * 4 + l4) * 16);
#pragma unroll
            for (int ct = 0; ct < 4; ct++)
                Bf[ct] = *(const short8*)(brow + ct * 16 * 512 + ks * 64);
#pragma unroll
            for (int mt = 0; mt < 4; mt++)
#pragma unroll
                for (int ct = 0; ct < 4; ct++)
                    acc[mt][ct] = __builtin_amdgcn_mfma_f32_16x16x32_bf16(
                        Af[mt], Bf[ct], acc[mt][ct], 0, 0, 0);
        }

        // write-combine into LDS: chunk = wv*16 + mt*4 + l4 (h-row, w/4), XOR low3 with o&7
#pragma unroll
        for (int ct = 0; ct < 4; ct++) {
            int o = ct * 16 + l15; int s = o & 7;
#pragma unroll
            for (int mt = 0; mt < 4; mt++) {
                int chunk = wv * 16 + mt * 4 + l4;
                *(f32x4*)(wb + o * 2048 + ((chunk ^ s) << 4)) = acc[mt][ct];
            }
        }
        __syncthreads();

        // readout: wave wv streams o in [wv*8, wv*8+8); each store instr = 1KB contiguous
        size_t outb = ((size_t)(n * 576 + t * 64) * 4 + rot) * 4096 + (size_t)h0 * 64;
#pragma unroll
        for (int oo = 0; oo < 8; oo++) {
            int o = wv * 8 + oo; int s = o & 7;
            float* obase = out + outb + (size_t)o * 16384;
#pragma unroll
            for (int half = 0; half < 2; half++) {
                int chunk = half * 64 + l;
                f32x4 v = *(const f32x4*)(wb + o * 2048 + ((chunk ^ s) << 4));
                *(f32x4*)(obase + chunk * 4) = v;
            }
        }
        __syncthreads();
    }
}

// ---------------- fallback (ws too small): direct fp32 ----------------
__global__ __launch_bounds__(256) void k_naive(const float* __restrict__ x,
                                               const float* __restrict__ wgt,
                                               float* __restrict__ out) {
    int idx = blockIdx.x * 256 + threadIdx.x;
    if (idx >= 75497472) return;
    int w = idx & 63, h = (idx >> 6) & 63, rot = (idx >> 12) & 3;
    int chn = idx >> 14; int ch = chn % 576; int n = chn / 576;
    int t = ch >> 6, o = ch & 63;
    int dy = 0, dx = 0;
    if (t > 0) {
        int ri = (t - 1 + 2 * rot) & 7;
        dy = ((27200 >> (2 * ri)) & 3) - 1;
        dx = ((1700 >> (2 * ri)) & 3) - 1;
    }
    int hh = h + dy, ww = w + dx;
    float acc = 0.f;
    if (hh >= 0 && hh < 64 && ww >= 0 && ww < 64) {
        for (int r = 0; r < 4; r++) {
            int rr = (r - rot) & 3;
            for (int c = 0; c < 64; c++)
                acc += x[(((n * 64 + c) * 4 + r) * 64 + hh) * 64 + ww] *
                       wgt[((o * 64 + c) * 4 + rr) * 9 + t];
        }
    }
    out[idx] = acc;
}

extern "C" void kernel_launch(void* const* d_in, const int* in_sizes, int n_in,
                              void* d_out, int out_size, void* d_ws, size_t ws_size,
                              hipStream_t stream) {
    const float* x = (const float*)d_in[0];
    const float* wgt = (const float*)d_in[1];
    float* out = (float*)d_out;
    const size_t XT_BYTES = (size_t)8 * 66 * 66 * 256 * 2;    // 17,842,176
    const size_t NEED = XT_BYTES + (size_t)9 * 256 * 256 * 2; // + 1,179,648
    if (ws_size < NEED) {
        k_naive<<<(75497472 + 255) / 256, 256, 0, stream>>>(x, wgt, out);
        return;
    }
    unsigned short* xt = (unsigned short*)d_ws;
    unsigned short* ball = (unsigned short*)((char*)d_ws + XT_BYTES);
    k_prep<<<3076, 256, 0, stream>>>(x, wgt, xt, ball);
    k_main<<<256, 512, 0, stream>>>(xt, ball, out);
}

// Round 7
// 103.952 us; speedup vs baseline: 1.7420x; 1.7420x over previous
//
#include <hip/hip_runtime.h>
#include <stdint.h>

using short8 = __attribute__((ext_vector_type(8))) short;
using f32x4  = __attribute__((ext_vector_type(4))) float;

__device__ __forceinline__ unsigned short f2bf(float f) {
    unsigned int u = __float_as_uint(f);
    unsigned int r = (u + 0x7fffu + ((u >> 16) & 1u)) >> 16;
    return (unsigned short)r;
}

// ---------------- prep: [0,512) transpose x -> x_t ; [512,640) zero pad rows ; [640,2944) build B ----------------
__global__ __launch_bounds__(256) void k_prep(const float* __restrict__ x,
                                              const float* __restrict__ wgt,
                                              unsigned short* __restrict__ xt,
                                              unsigned short* __restrict__ ball) {
    __shared__ unsigned short sm[256][72];
    int b = blockIdx.x;
    int tid = threadIdx.x;
    if (b < 512) {
        int n = b >> 6; int h = b & 63;
        int c = tid >> 2, r = tid & 3; int k = r * 64 + c;
        const float* src = x + ((((size_t)n * 64 + c) * 4 + r) * 64 + h) * 64;
#pragma unroll
        for (int i = 0; i < 64; i += 4) {
            float4 v = *(const float4*)(src + i);
            sm[k][i + 0] = f2bf(v.x); sm[k][i + 1] = f2bf(v.y);
            sm[k][i + 2] = f2bf(v.z); sm[k][i + 3] = f2bf(v.w);
        }
        __syncthreads();
        int w = tid & 63, kg = tid >> 6;
        unsigned short* dst = xt + ((size_t)(n * 66 + (h + 1)) * 64 + w) * 256;
        int key = (w + 1) & 7;
#pragma unroll
        for (int cc = 0; cc < 8; cc++) {
            int s = kg * 8 + cc; int sp = s ^ key;
            short8 v;
#pragma unroll
            for (int e = 0; e < 8; e++) v[e] = (short)sm[s * 8 + e][w];
            *(short8*)(dst + sp * 8) = v;
        }
    } else if (b < 640) {
        int idx = (b - 512) * 256 + tid;
        int n = idx >> 12; int rr = (idx >> 11) & 1; int cpos = idx & 2047;
        f32x4 z = {0.f, 0.f, 0.f, 0.f};
        *(f32x4*)((char*)xt + (size_t)(n * 66 + (rr ? 65 : 0)) * 32768 + cpos * 16) = z;
    } else {
        int idx = (b - 640) * 256 + tid;
        int k = idx & 255; int col = (idx >> 8) & 255; int j = idx >> 16;
        int rot = col >> 6, o = col & 63;
        int r = k >> 6, c = k & 63;
        int t = (j == 0) ? 0 : (1 + ((j - 1 - 2 * rot) & 7));
        float v = wgt[((o * 64 + c) * 4 + ((r - rot) & 3)) * 9 + t];
        ball[idx] = f2bf(v);
    }
}

// main: R4 structure + per-wave 2KB write-combine slices (single-instr 512B store runs).
__global__ __launch_bounds__(512) void k_main(const unsigned short* __restrict__ xt,
                                              const unsigned short* __restrict__ ball,
                                              float* __restrict__ out) {
    extern __shared__ char lds[];                      // 135168 A-panel + 8*2048 WC = 151552
    int blk = blockIdx.x; int n = blk >> 5; int h0 = (blk & 31) * 2;
    int tid = threadIdx.x;

    // stage 4 x_t rows via async global->LDS (R4-verbatim)
    const char* xbase = (const char*)xt;
#pragma unroll
    for (int i = 0; i < 16; i++) {
        int chunk = tid + i * 512;
        int r4 = chunk >> 11; int cin = chunk & 2047;
        const char* src = xbase + (size_t)(n * 66 + h0 + r4) * 32768 + cin * 16;
        char* dst = lds + r4 * 33792 + 512 + cin * 16;
        __builtin_amdgcn_global_load_lds(
            (const __attribute__((address_space(1))) unsigned int*)src,
            (__attribute__((address_space(3))) unsigned int*)dst, 16, 0, 0);
    }
    if (tid < 256) {                                   // zero the w-halo slots (ws=0, ws=65)
        int r4 = tid >> 6; int sp = (tid >> 5) & 1; int cc = tid & 31;
        f32x4 z = {0.f, 0.f, 0.f, 0.f};
        *(f32x4*)(lds + r4 * 33792 + (sp ? 65 * 512 : 0) + cc * 16) = z;
    }
    __syncthreads();

    int wv = tid >> 6; int l = tid & 63; int l15 = l & 15; int l4 = l >> 4;
    int rot = wv >> 1;                                 // wave owns cols [wv*32, wv*32+32)
    const char* bb = (const char*)ball;
    char* slice = lds + 135168 + wv * 2048;            // per-wave WC slice: 4 o-rows x 512B
    const int KEY[4] = {0, 5, 2, 7};                   // bank-spread XOR per o-row

    for (int j = 0; j < 9; j++) {
        int dy = ((0x1A901 >> (2 * j)) & 3) - 1;
        int dx = ((0x01A91 >> (2 * j)) & 3) - 1;
        int t = (j == 0) ? 0 : (1 + ((j - 1 - 2 * rot) & 7));

        short8 Bf[2][8];
#pragma unroll
        for (int ct = 0; ct < 2; ct++) {
            int col = wv * 32 + ct * 16 + l15;
            const char* bp = bb + j * 131072 + col * 512 + l4 * 16;
#pragma unroll
            for (int ks = 0; ks < 8; ks++) Bf[ct][ks] = *(const short8*)(bp + ks * 64);
        }

        f32x4 acc[4][2][2];                            // [mtp][ct][m2], all-static indexing
#pragma unroll
        for (int a = 0; a < 4; a++)
#pragma unroll
            for (int b2 = 0; b2 < 2; b2++)
#pragma unroll
                for (int c2 = 0; c2 < 2; c2++) acc[a][b2][c2] = (f32x4){0.f, 0.f, 0.f, 0.f};

#pragma unroll
        for (int mtp = 0; mtp < 4; mtp++) {
            short8 Af[2][8];
#pragma unroll
            for (int m2 = 0; m2 < 2; m2++) {
                int mt = mtp * 2 + m2;
                int pixel = mt * 16 + l15;
                int r4 = (pixel >> 6) + dy + 1;
                int ws = (pixel & 63) + dx + 1;
                const char* ap = lds + (r4 * 66 + ws) * 512;
                int key = ws & 7;
#pragma unroll
                for (int ks = 0; ks < 8; ks++) {
                    int s = ks * 4 + l4;
                    Af[m2][ks] = *(const short8*)(ap + ((s ^ key) << 4));
                }
            }
#pragma unroll
            for (int ks = 0; ks < 8; ks++)
#pragma unroll
                for (int ct = 0; ct < 2; ct++)
#pragma unroll
                    for (int m2 = 0; m2 < 2; m2++)
                        acc[mtp][ct][m2] = __builtin_amdgcn_mfma_f32_16x16x32_bf16(
                            Af[m2][ks], Bf[ct][ks], acc[mtp][ct][m2], 0, 0, 0);
        }

        // WC flush: 8 rounds x 4 o-rows; each store instr = 2 x 512B contiguous segments
        size_t outb = ((size_t)(n * 576 + t * 64) * 4 + rot) * 4096 + (size_t)h0 * 64;
#pragma unroll
        for (int r = 0; r < 8; r++) {
            int ct = r >> 2; int q = r & 3;
            if ((l15 >> 2) == q) {                     // 16 lanes own these 4 o-rows
                int orow = l15 & 3;
#pragma unroll
                for (int mtp = 0; mtp < 4; mtp++)
#pragma unroll
                    for (int m2 = 0; m2 < 2; m2++) {
                        int chunk = (mtp * 2 + m2) * 4 + l4;   // pixel/4
                        *(f32x4*)(slice + orow * 512 + ((chunk ^ KEY[orow]) << 4)) =
                            acc[mtp][ct][m2];
                    }
            }
            __builtin_amdgcn_sched_barrier(0);         // pin write->read order (HW DS is in-order)
            int o8 = ct * 16 + q * 4;
#pragma unroll
            for (int i = 0; i < 2; i++) {
                int o_loc = o8 + 2 * i + (l >> 5);
                int orow = o_loc & 3;
                f32x4 v = *(const f32x4*)(slice + orow * 512 + (((l & 31) ^ KEY[orow]) << 4));
                int o = (wv & 1) * 32 + o_loc;
                *(f32x4*)(out + outb + (size_t)o * 16384 + (l & 31) * 4) = v;
            }
            __builtin_amdgcn_sched_barrier(0);         // next round rewrites the slice
        }
    }
}

// ---------------- fallback (ws too small): direct fp32 ----------------
__global__ __launch_bounds__(256) void k_naive(const float* __restrict__ x,
                                               const float* __restrict__ wgt,
                                               float* __restrict__ out) {
    int idx = blockIdx.x * 256 + threadIdx.x;
    if (idx >= 75497472) return;
    int w = idx & 63, h = (idx >> 6) & 63, rot = (idx >> 12) & 3;
    int chn = idx >> 14; int ch = chn % 576; int n = chn / 576;
    int t = ch >> 6, o = ch & 63;
    int dy = 0, dx = 0;
    if (t > 0) {
        int ri = (t - 1 + 2 * rot) & 7;
        dy = ((27200 >> (2 * ri)) & 3) - 1;
        dx = ((1700 >> (2 * ri)) & 3) - 1;
    }
    int hh = h + dy, ww = w + dx;
    float acc = 0.f;
    if (hh >= 0 && hh < 64 && ww >= 0 && ww < 64) {
        for (int r = 0; r < 4; r++) {
            int rr = (r - rot) & 3;
            for (int c = 0; c < 64; c++)
                acc += x[(((n * 64 + c) * 4 + r) * 64 + hh) * 64 + ww] *
                       wgt[((o * 64 + c) * 4 + rr) * 9 + t];
        }
    }
    out[idx] = acc;
}

extern "C" void kernel_launch(void* const* d_in, const int* in_sizes, int n_in,
                              void* d_out, int out_size, void* d_ws, size_t ws_size,
                              hipStream_t stream) {
    const float* x = (const float*)d_in[0];
    const float* wgt = (const float*)d_in[1];
    float* out = (float*)d_out;
    const size_t XT_BYTES = (size_t)8 * 66 * 64 * 256 * 2;    // 17,301,504
    const size_t NEED = XT_BYTES + (size_t)9 * 256 * 256 * 2; // + 1,179,648
    if (ws_size < NEED) {
        k_naive<<<(75497472 + 255) / 256, 256, 0, stream>>>(x, wgt, out);
        return;
    }
    unsigned short* xt = (unsigned short*)d_ws;
    unsigned short* ball = (unsigned short*)((char*)d_ws + XT_BYTES);
    k_prep<<<2944, 256, 0, stream>>>(x, wgt, xt, ball);
    k_main<<<256, 512, 151552, stream>>>(xt, ball, out);
}